// Round 2
// baseline (380.126 us; speedup 1.0000x reference)
//
#include <hip/hip_runtime.h>
#include <stddef.h>

#define BB 32
#define NN 1024
#define DD 128
#define HH 128

using f32x4 = __attribute__((ext_vector_type(4))) float;
using f16x8 = __attribute__((ext_vector_type(8))) _Float16;
using f16x4 = __attribute__((ext_vector_type(4))) _Float16;

// ---------------- Projection kernel: q,k (row-major f16), vT (transposed f16) ----------
// grid: 1024 blocks (32 rows each), 256 threads. Pass order q,k,v so the vT
// transpose can alias the xs buffer after its last use.
__global__ __launch_bounds__(256) void proj_kernel(
    const float* __restrict__ x,
    const float* __restrict__ Wv, const float* __restrict__ bv,
    const float* __restrict__ Wk, const float* __restrict__ bk,
    const float* __restrict__ Wq, const float* __restrict__ bq,
    _Float16* __restrict__ qo, _Float16* __restrict__ ko, _Float16* __restrict__ vTo)
{
    __shared__ __align__(16) float xs[32 * 128];   // 16 KB (aliased by vT transpose in pass 2)
    __shared__ __align__(16) float Wl[128 * 128];  // 64 KB
    const int tid  = threadIdx.x;
    const int row0 = blockIdx.x * 32;           // flat row in [0, B*N)
    const int b    = row0 >> 10;
    const int n0   = row0 & 1023;

    // stage x tile (coalesced float4)
    {
        const f32x4* xg = (const f32x4*)(x + (size_t)row0 * 128);
        f32x4* xs4 = (f32x4*)xs;
        for (int i = tid; i < 1024; i += 256) xs4[i] = xg[i];
    }

    const int h4 = tid & 31;   // h chunk: h = h4*4 .. h4*4+3
    const int rg = tid >> 5;   // row group: rows rg*4 .. rg*4+3

    for (int p = 0; p < 3; ++p) {
        const float* W    = (p == 0) ? Wq : ((p == 1) ? Wk : Wv);
        const float* bias = (p == 0) ? bq : ((p == 1) ? bk : bv);
        __syncthreads();                         // previous pass done reading Wl
        {
            const f32x4* Wg = (const f32x4*)W;
            f32x4* Wl4 = (f32x4*)Wl;
            for (int i = tid; i < 4096; i += 256) Wl4[i] = Wg[i];
        }
        __syncthreads();

        const f32x4* xs4 = (const f32x4*)xs;
        const f32x4* Wl4 = (const f32x4*)Wl;
        f32x4 bias4 = ((const f32x4*)bias)[h4];
        f32x4 acc[4];
        #pragma unroll
        for (int r = 0; r < 4; ++r) acc[r] = bias4;

        #pragma unroll 4
        for (int d4 = 0; d4 < 32; ++d4) {
            f32x4 w0 = Wl4[(d4 * 4 + 0) * 32 + h4];
            f32x4 w1 = Wl4[(d4 * 4 + 1) * 32 + h4];
            f32x4 w2 = Wl4[(d4 * 4 + 2) * 32 + h4];
            f32x4 w3 = Wl4[(d4 * 4 + 3) * 32 + h4];
            #pragma unroll
            for (int r = 0; r < 4; ++r) {
                f32x4 xv = xs4[(rg * 4 + r) * 32 + d4];
                acc[r] += xv[0] * w0 + xv[1] * w1 + xv[2] * w2 + xv[3] * w3;
            }
        }

        if (p < 2) {
            _Float16* dst = (p == 0) ? qo : ko;
            #pragma unroll
            for (int r = 0; r < 4; ++r) {
                int row = rg * 4 + r;
                f32x4 a = acc[r];
                f16x4 hv;
                #pragma unroll
                for (int j = 0; j < 4; ++j) hv[j] = (_Float16)fmaxf(a[j], 0.0f);
                *(f16x4*)&dst[(size_t)(row0 + row) * 128 + h4 * 4] = hv;
            }
        } else {
            // v pass: transpose through LDS (aliasing xs — xs reads are done)
            __syncthreads();
            _Float16* vsm = (_Float16*)xs;   // layout [h][n], stride 40 f16 (80 B, 16B-aligned)
            #pragma unroll
            for (int r = 0; r < 4; ++r) {
                int row = rg * 4 + r;
                f32x4 a = acc[r];
                #pragma unroll
                for (int j = 0; j < 4; ++j)
                    vsm[(h4 * 4 + j) * 40 + row] = (_Float16)fmaxf(a[j], 0.0f);
            }
            __syncthreads();
            // coalesced global write: 128 h-rows x 32 n (64 B per row)
            for (int c = tid; c < 512; c += 256) {
                int h = c >> 2, g = c & 3;
                f16x8 val = *(const f16x8*)&vsm[h * 40 + g * 8];
                *(f16x8*)&vTo[(size_t)b * HH * NN + (size_t)h * NN + n0 + g * 8] = val;
            }
        }
    }
}

// ---------------- Fused attention kernel (flash-style, f16 MFMA, barrier-free) --------
// grid: (N/64, B); block 256 = 4 waves; wave w owns rows i0 = bx*64 + w*16.
// K/V fragments load DIRECTLY from global (B-layout loads are fully coalesced:
// 4 lanes x 16B = one 64B line per row). No __syncthreads anywhere — the only
// LDS use is the wave-private P C-layout -> A-layout round trip.
__global__ __launch_bounds__(256) void attn_kernel(
    const _Float16* __restrict__ q, const _Float16* __restrict__ k,
    const _Float16* __restrict__ vT, const float* __restrict__ mask,
    float* __restrict__ out)
{
    __shared__ __align__(16) _Float16 ps[4][16 * 40];   // per-wave P tile, row stride 40 f16

    const int tid = threadIdx.x;
    const int w   = tid >> 6;
    const int ln  = tid & 63;
    const int qd  = ln >> 4;       // quad 0..3
    const int l16 = ln & 15;
    const int b   = blockIdx.y;
    const int i0  = blockIdx.x * 64 + w * 16;

    // Q A-fragments (rows i0+l16, k = t*32 + qd*8 + j)
    f16x8 qf[4];
    {
        const _Float16* qrow = q + ((size_t)b * NN + i0 + l16) * 128;
        #pragma unroll
        for (int t = 0; t < 4; ++t)
            qf[t] = *(const f16x8*)(qrow + t * 32 + qd * 8);
    }

    const _Float16* kbase = k  + (size_t)b * NN * 128;
    const _Float16* vbase = vT + (size_t)b * HH * NN;
    const float*    mrow  = mask + (size_t)b * NN * NN + (size_t)(i0 + qd * 4) * NN;

    f32x4 acc[8];
    #pragma unroll
    for (int hc = 0; hc < 8; ++hc) acc[hc] = (f32x4)(0.0f);
    float m_i[4], l_i[4];
    #pragma unroll
    for (int r = 0; r < 4; ++r) { m_i[r] = -1e30f; l_i[r] = 0.0f; }

    // preload tile 0: K fragments + mask
    f16x8 kc[8];
    float mc[8];
    #pragma unroll
    for (int c = 0; c < 2; ++c)
        #pragma unroll
        for (int t = 0; t < 4; ++t)
            kc[c * 4 + t] = *(const f16x8*)(kbase + (size_t)(c * 16 + l16) * 128 + t * 32 + qd * 8);
    #pragma unroll
    for (int c = 0; c < 2; ++c)
        #pragma unroll
        for (int r = 0; r < 4; ++r)
            mc[c * 4 + r] = mrow[(size_t)r * NN + c * 16 + l16];

    for (int jt = 0; jt < 32; ++jt) {
        const int j0 = jt * 32;
        const int jn = (jt < 31) ? j0 + 32 : 0;   // next-tile prefetch (wraps harmlessly)

        // prefetch next K fragments + mask into registers (in flight during compute)
        f16x8 kn[8];
        float mn[8];
        #pragma unroll
        for (int c = 0; c < 2; ++c)
            #pragma unroll
            for (int t = 0; t < 4; ++t)
                kn[c * 4 + t] = *(const f16x8*)(kbase + (size_t)(jn + c * 16 + l16) * 128 + t * 32 + qd * 8);
        #pragma unroll
        for (int c = 0; c < 2; ++c)
            #pragma unroll
            for (int r = 0; r < 4; ++r)
                mn[c * 4 + r] = mrow[(size_t)r * NN + jn + c * 16 + l16];

        // V fragments for the current tile — issued early, consumed after softmax
        f16x8 vc[8];
        #pragma unroll
        for (int hc = 0; hc < 8; ++hc)
            vc[hc] = *(const f16x8*)(vbase + (size_t)(hc * 16 + l16) * NN + j0 + qd * 8);

        // S = Q * K^T  (two 16x16 col-chunks)
        f32x4 s0 = (f32x4)(0.0f), s1 = (f32x4)(0.0f);
        #pragma unroll
        for (int t = 0; t < 4; ++t) {
            s0 = __builtin_amdgcn_mfma_f32_16x16x32_f16(qf[t], kc[t],     s0, 0, 0, 0);
            s1 = __builtin_amdgcn_mfma_f32_16x16x32_f16(qf[t], kc[4 + t], s1, 0, 0, 0);
        }

        // mask + online softmax (rows split across quads: row = qd*4 + r)
        float scale[4];
        #pragma unroll
        for (int r = 0; r < 4; ++r) {
            float lg0 = (mc[r]     != 0.0f) ? s0[r] : -1e30f;
            float lg1 = (mc[4 + r] != 0.0f) ? s1[r] : -1e30f;
            float mx = fmaxf(lg0, lg1);
            mx = fmaxf(mx, __shfl_xor(mx, 1));
            mx = fmaxf(mx, __shfl_xor(mx, 2));
            mx = fmaxf(mx, __shfl_xor(mx, 4));
            mx = fmaxf(mx, __shfl_xor(mx, 8));
            float mnew = fmaxf(m_i[r], mx);
            float p0 = __expf(lg0 - mnew);
            float p1 = __expf(lg1 - mnew);
            float rs = p0 + p1;
            rs += __shfl_xor(rs, 1);
            rs += __shfl_xor(rs, 2);
            rs += __shfl_xor(rs, 4);
            rs += __shfl_xor(rs, 8);
            float sc = __expf(m_i[r] - mnew);
            l_i[r] = l_i[r] * sc + rs;
            m_i[r] = mnew;
            scale[r] = sc;
            ps[w][(qd * 4 + r) * 40 + l16]      = (_Float16)p0;
            ps[w][(qd * 4 + r) * 40 + 16 + l16] = (_Float16)p1;
        }

        // rescale accumulators
        #pragma unroll
        for (int hc = 0; hc < 8; ++hc) {
            #pragma unroll
            for (int r = 0; r < 4; ++r) acc[hc][r] *= scale[r];
        }

        // PV: A = P (wave-private LDS round trip, C-layout -> A-layout), B = vT rows
        f16x8 pa = *(const f16x8*)&ps[w][l16 * 40 + qd * 8];
        #pragma unroll
        for (int hc = 0; hc < 8; ++hc)
            acc[hc] = __builtin_amdgcn_mfma_f32_16x16x32_f16(pa, vc[hc], acc[hc], 0, 0, 0);

        // rotate pipeline registers
        #pragma unroll
        for (int i = 0; i < 8; ++i) { kc[i] = kn[i]; mc[i] = mn[i]; }
    }

    // epilogue: out = acc / l
    float inv[4];
    #pragma unroll
    for (int r = 0; r < 4; ++r) inv[r] = 1.0f / l_i[r];
    #pragma unroll
    for (int hc = 0; hc < 8; ++hc) {
        #pragma unroll
        for (int r = 0; r < 4; ++r) {
            out[((size_t)b * NN + i0 + qd * 4 + r) * 128 + hc * 16 + l16] = acc[hc][r] * inv[r];
        }
    }
}

extern "C" void kernel_launch(void* const* d_in, const int* in_sizes, int n_in,
                              void* d_out, int out_size, void* d_ws, size_t ws_size,
                              hipStream_t stream) {
    const float* x    = (const float*)d_in[0];
    const float* mask = (const float*)d_in[1];
    const float* Wv   = (const float*)d_in[2];
    const float* bv   = (const float*)d_in[3];
    const float* Wk   = (const float*)d_in[4];
    const float* bk   = (const float*)d_in[5];
    const float* Wq   = (const float*)d_in[6];
    const float* bq   = (const float*)d_in[7];
    float* out = (float*)d_out;

    const size_t BNH = (size_t)BB * NN * HH;   // 4,194,304 elements
    _Float16* ws  = (_Float16*)d_ws;
    _Float16* vTb = ws;                 // [B][H][N]
    _Float16* kb  = ws + BNH;           // [B][N][H]
    _Float16* qb  = ws + 2 * BNH;       // [B][N][H]

    proj_kernel<<<1024, 256, 0, stream>>>(x, Wv, bv, Wk, bk, Wq, bq, qb, kb, vTb);
    attn_kernel<<<dim3(16, 32), 256, 0, stream>>>(qb, kb, vTb, mask, out);
}

// Round 3
// 332.419 us; speedup vs baseline: 1.1435x; 1.1435x over previous
//
#include <hip/hip_runtime.h>
#include <stddef.h>

#define BB 32
#define NN 1024
#define HH 128

using f32x4 = __attribute__((ext_vector_type(4))) float;
using f16x8 = __attribute__((ext_vector_type(8))) _Float16;

// W^T in fp16, [p][n][k] = W_p[k][n]; p: 0=q, 1=k, 2=v. Static device global
// (no hipMalloc needed; safe under graph capture).
__device__ _Float16 g_WT[3 * 128 * 128];

// ---------------- W transpose + cast to fp16 (tiny: 3 blocks) ----------------
__global__ __launch_bounds__(256) void wtrans_kernel(const float* __restrict__ Wq,
                                                     const float* __restrict__ Wk,
                                                     const float* __restrict__ Wv) {
    __shared__ float wl[128 * 128];
    const float* W = (blockIdx.x == 0) ? Wq : (blockIdx.x == 1) ? Wk : Wv;
    _Float16* dst = g_WT + blockIdx.x * 16384;
    const int tid = threadIdx.x;
    for (int i = tid; i < 4096; i += 256) ((f32x4*)wl)[i] = ((const f32x4*)W)[i];
    __syncthreads();
    for (int s = 0; s < 8; ++s) {
        int ch = tid + s * 256;
        int n = ch >> 4, kc = ch & 15;
        f16x8 v;
        #pragma unroll
        for (int j = 0; j < 8; ++j) v[j] = (_Float16)wl[(kc * 8 + j) * 128 + n];
        *(f16x8*)&dst[n * 128 + kc * 8] = v;
    }
}

// ---------------- Projection via MFMA ----------------
// grid 512 blocks (64 rows each), 256 thr = 4 waves (16 rows/wave).
// A-frags: x rows cast to fp16 (loaded once, reused for all 3 GEMMs).
// B-frags: g_WT rows, direct from global (L2-resident, fully coalesced 16B).
__global__ __launch_bounds__(256) void proj_kernel(
    const float* __restrict__ x,
    const float* __restrict__ bq, const float* __restrict__ bk, const float* __restrict__ bv,
    _Float16* __restrict__ qo, _Float16* __restrict__ ko, _Float16* __restrict__ vTo)
{
    __shared__ __align__(16) _Float16 rep[4][16 * 136];   // wave-private q/k repack (17.4 KB)
    __shared__ __align__(16) _Float16 vsm[128 * 72];      // block vT repack (18.4 KB)
    const int tid = threadIdx.x;
    const int w = tid >> 6, ln = tid & 63, qd = ln >> 4, l16 = ln & 15;
    const int row0 = blockIdx.x * 64;
    const int rw = row0 + w * 16;
    const int b = row0 >> 10, n0 = row0 & 1023;

    // A fragments: rows rw+l16, k = t*32 + qd*8 + j
    f16x8 xa[4];
    {
        const float* xr = x + (size_t)(rw + l16) * 128;
        #pragma unroll
        for (int t = 0; t < 4; ++t) {
            f32x4 a0 = *(const f32x4*)(xr + t * 32 + qd * 8);
            f32x4 a1 = *(const f32x4*)(xr + t * 32 + qd * 8 + 4);
            #pragma unroll
            for (int j = 0; j < 4; ++j) { xa[t][j] = (_Float16)a0[j]; xa[t][4 + j] = (_Float16)a1[j]; }
        }
    }

    for (int p = 0; p < 3; ++p) {
        const _Float16* Wt = g_WT + p * 16384;
        const float* bias = (p == 0) ? bq : (p == 1) ? bk : bv;

        float bv_[8];
        #pragma unroll
        for (int hc = 0; hc < 8; ++hc) bv_[hc] = bias[hc * 16 + l16];

        f32x4 acc[8];
        #pragma unroll
        for (int hc = 0; hc < 8; ++hc) {
            acc[hc] = (f32x4)(0.0f);
            #pragma unroll
            for (int t = 0; t < 4; ++t) {
                f16x8 bf = *(const f16x8*)(Wt + (size_t)(hc * 16 + l16) * 128 + t * 32 + qd * 8);
                acc[hc] = __builtin_amdgcn_mfma_f32_16x16x32_f16(xa[t], bf, acc[hc], 0, 0, 0);
            }
        }

        if (p < 2) {
            _Float16* dst = (p == 0) ? qo : ko;
            // C-layout -> row-major via wave-private LDS (no barrier needed)
            #pragma unroll
            for (int hc = 0; hc < 8; ++hc)
                #pragma unroll
                for (int r = 0; r < 4; ++r)
                    rep[w][(qd * 4 + r) * 136 + hc * 16 + l16] =
                        (_Float16)fmaxf(acc[hc][r] + bv_[hc], 0.0f);
            #pragma unroll
            for (int s = 0; s < 4; ++s) {
                int ch = ln + s * 64;
                int rr = ch >> 4, kc = ch & 15;
                f16x8 v = *(const f16x8*)&rep[w][rr * 136 + kc * 8];
                *(f16x8*)&dst[(size_t)(rw + rr) * 128 + kc * 8] = v;
            }
        } else {
            // v pass: block-wide transpose to vT[b][h][n]
            #pragma unroll
            for (int hc = 0; hc < 8; ++hc)
                #pragma unroll
                for (int r = 0; r < 4; ++r)
                    vsm[(hc * 16 + l16) * 72 + w * 16 + qd * 4 + r] =
                        (_Float16)fmaxf(acc[hc][r] + bv_[hc], 0.0f);
            __syncthreads();
            #pragma unroll
            for (int s = 0; s < 4; ++s) {
                int ch = tid + s * 256;
                int h = ch >> 3, g = ch & 7;
                f16x8 v = *(const f16x8*)&vsm[h * 72 + g * 8];
                *(f16x8*)&vTo[(size_t)b * HH * NN + (size_t)h * NN + n0 + g * 8] = v;
            }
        }
    }
}

// ---------------- Fused attention, j-split in-block ----------------
// grid (32, 32): blockIdx.x = 32-row group, blockIdx.y = batch. 256 thr = 4 waves.
// pair = w>>1 (16 rows), half = w&1 (512 j-cols, 16 tiles of 32).
// K double-buffered in LDS (both halves staged cooperatively); V direct from L2.
// Per-iter global issue order: V(current) -> K(next) -> mask(jt+2), so waiting
// on V (in-order vmcnt) never drains the K/mask prefetch.
__global__ __launch_bounds__(256, 3) void attn_kernel(
    const _Float16* __restrict__ q, const _Float16* __restrict__ k,
    const _Float16* __restrict__ vT, const float* __restrict__ mask,
    float* __restrict__ out)
{
    __shared__ __align__(16) unsigned char smem[39936];
    _Float16* ks = (_Float16*)smem;                 // [buf][half][32*136] = 34816 B
    _Float16* ps = (_Float16*)(smem + 34816);       // [4][16*40] = 5120 B
    float* mg = (float*)smem;                        // merge overlay (after K-loop)

    const int tid = threadIdx.x;
    const int w = tid >> 6, ln = tid & 63, qd = ln >> 4, l16 = ln & 15;
    const int pair = w >> 1, half = w & 1;
    const int b = blockIdx.y;
    const int iw = blockIdx.x * 32 + pair * 16;

    _Float16* psw = ps + w * 640;

    // Q A-fragments
    f16x8 qf[4];
    {
        const _Float16* qrow = q + ((size_t)b * NN + iw + l16) * 128;
        #pragma unroll
        for (int t = 0; t < 4; ++t)
            qf[t] = *(const f16x8*)(qrow + t * 32 + qd * 8);
    }

    const _Float16* kbase = k + (size_t)b * NN * 128;
    const _Float16* vbase = vT + (size_t)b * HH * NN + half * 512;
    const float* mrow = mask + (size_t)b * NN * NN + (size_t)(iw + qd * 4) * NN + half * 512;

    f32x4 acc[8];
    #pragma unroll
    for (int hc = 0; hc < 8; ++hc) acc[hc] = (f32x4)(0.0f);
    float m_i[4], l_i[4];
    #pragma unroll
    for (int r = 0; r < 4; ++r) { m_i[r] = -1e30f; l_i[r] = 0.0f; }

    // pre-stage K tile 0 (both halves) into buf 0
    #pragma unroll
    for (int s = 0; s < 4; ++s) {
        int ch = tid + s * 256;
        int sh = ch >> 9, rowi = (ch >> 4) & 31, cc = ch & 15;
        f16x8 v = *(const f16x8*)(kbase + (size_t)(sh * 512 + rowi) * 128 + cc * 8);
        *(f16x8*)&ks[(size_t)sh * 4352 + rowi * 136 + cc * 8] = v;
    }
    float mc[8], mn[8];
    #pragma unroll
    for (int c = 0; c < 2; ++c)
        #pragma unroll
        for (int r = 0; r < 4; ++r) {
            mc[c * 4 + r] = mrow[(size_t)r * NN + c * 16 + l16];
            mn[c * 4 + r] = mrow[(size_t)r * NN + 32 + c * 16 + l16];
        }
    int buf = 0;

    for (int jt = 0; jt < 16; ++jt) {
        __syncthreads();                       // staged ks[buf] visible to all
        const bool hasK = (jt < 15);

        // (1) V fragments for CURRENT tile — issued first (in-order vmcnt!)
        f16x8 vc[8];
        #pragma unroll
        for (int hc = 0; hc < 8; ++hc)
            vc[hc] = *(const f16x8*)(vbase + (size_t)(hc * 16 + l16) * NN + jt * 32 + qd * 8);

        // (2) next K tile -> regs (written to LDS at end of iter)
        f16x8 kst[4];
        if (hasK) {
            #pragma unroll
            for (int s = 0; s < 4; ++s) {
                int ch = tid + s * 256;
                int sh = ch >> 9, rowi = (ch >> 4) & 31, cc = ch & 15;
                kst[s] = *(const f16x8*)(kbase + (size_t)(sh * 512 + (jt + 1) * 32 + rowi) * 128 + cc * 8);
            }
        }

        // (3) mask tile jt+2 (2-deep prefetch of the HBM stream)
        float mn2[8];
        if (jt < 14) {
            #pragma unroll
            for (int c = 0; c < 2; ++c)
                #pragma unroll
                for (int r = 0; r < 4; ++r)
                    mn2[c * 4 + r] = mrow[(size_t)r * NN + (jt + 2) * 32 + c * 16 + l16];
        } else {
            #pragma unroll
            for (int i = 0; i < 8; ++i) mn2[i] = 0.0f;
        }

        // (4) S = Q K^T from LDS
        const _Float16* ksb = ks + (size_t)(buf * 2 + half) * 4352;
        f32x4 s0 = (f32x4)(0.0f), s1 = (f32x4)(0.0f);
        #pragma unroll
        for (int t = 0; t < 4; ++t) {
            f16x8 b0 = *(const f16x8*)&ksb[(l16) * 136 + t * 32 + qd * 8];
            f16x8 b1 = *(const f16x8*)&ksb[(16 + l16) * 136 + t * 32 + qd * 8];
            s0 = __builtin_amdgcn_mfma_f32_16x16x32_f16(qf[t], b0, s0, 0, 0, 0);
            s1 = __builtin_amdgcn_mfma_f32_16x16x32_f16(qf[t], b1, s1, 0, 0, 0);
        }

        // (5) mask + online softmax
        float scale[4];
        #pragma unroll
        for (int r = 0; r < 4; ++r) {
            float lg0 = (mc[r] != 0.0f) ? s0[r] : -1e30f;
            float lg1 = (mc[4 + r] != 0.0f) ? s1[r] : -1e30f;
            float mx = fmaxf(lg0, lg1);
            mx = fmaxf(mx, __shfl_xor(mx, 1));
            mx = fmaxf(mx, __shfl_xor(mx, 2));
            mx = fmaxf(mx, __shfl_xor(mx, 4));
            mx = fmaxf(mx, __shfl_xor(mx, 8));
            float mnew = fmaxf(m_i[r], mx);
            float p0 = __expf(lg0 - mnew);
            float p1 = __expf(lg1 - mnew);
            float rs = p0 + p1;
            rs += __shfl_xor(rs, 1);
            rs += __shfl_xor(rs, 2);
            rs += __shfl_xor(rs, 4);
            rs += __shfl_xor(rs, 8);
            float sc = __expf(m_i[r] - mnew);
            l_i[r] = l_i[r] * sc + rs;
            m_i[r] = mnew;
            scale[r] = sc;
            psw[(qd * 4 + r) * 40 + l16]      = (_Float16)p0;
            psw[(qd * 4 + r) * 40 + 16 + l16] = (_Float16)p1;
        }

        // (6) rescale
        #pragma unroll
        for (int hc = 0; hc < 8; ++hc)
            #pragma unroll
            for (int r = 0; r < 4; ++r) acc[hc][r] *= scale[r];

        // (7) PV
        f16x8 pa = *(const f16x8*)&psw[l16 * 40 + qd * 8];
        #pragma unroll
        for (int hc = 0; hc < 8; ++hc)
            acc[hc] = __builtin_amdgcn_mfma_f32_16x16x32_f16(pa, vc[hc], acc[hc], 0, 0, 0);

        // (8) write staged K to the other buffer (visible after next barrier)
        if (hasK) {
            #pragma unroll
            for (int s = 0; s < 4; ++s) {
                int ch = tid + s * 256;
                int sh = ch >> 9, rowi = (ch >> 4) & 31, cc = ch & 15;
                *(f16x8*)&ks[(size_t)((buf ^ 1) * 2 + sh) * 4352 + rowi * 136 + cc * 8] = kst[s];
            }
        }

        #pragma unroll
        for (int i = 0; i < 8; ++i) { mc[i] = mn[i]; mn[i] = mn2[i]; }
        buf ^= 1;
    }

    // ---- merge the two j-halves (in-LDS, overlay on ks) ----
    __syncthreads();
    // mg layout: acc area: [pair][row16][col128] floats (4096), then m/l at 4096..
    float* ml = mg + 4096;
    if (half == 1) {
        #pragma unroll
        for (int hc = 0; hc < 8; ++hc)
            #pragma unroll
            for (int r = 0; r < 4; ++r)
                mg[pair * 2048 + (qd * 4 + r) * 128 + hc * 16 + l16] = acc[hc][r];
        if (l16 == 0) {
            #pragma unroll
            for (int r = 0; r < 4; ++r) {
                ml[pair * 32 + qd * 4 + r]      = m_i[r];
                ml[64 + pair * 32 + qd * 4 + r] = l_i[r];
            }
        }
    }
    __syncthreads();
    if (half == 0) {
        float a0s[4], a1s[4], inv[4];
        #pragma unroll
        for (int r = 0; r < 4; ++r) {
            float m1 = ml[pair * 32 + qd * 4 + r];
            float l1 = ml[64 + pair * 32 + qd * 4 + r];
            float ms = fmaxf(m_i[r], m1);
            a0s[r] = __expf(m_i[r] - ms);
            a1s[r] = __expf(m1 - ms);
            inv[r] = 1.0f / (l_i[r] * a0s[r] + l1 * a1s[r]);
        }
        #pragma unroll
        for (int hc = 0; hc < 8; ++hc)
            #pragma unroll
            for (int r = 0; r < 4; ++r) {
                float o = (acc[hc][r] * a0s[r] +
                           mg[pair * 2048 + (qd * 4 + r) * 128 + hc * 16 + l16] * a1s[r]) * inv[r];
                out[((size_t)b * NN + iw + qd * 4 + r) * 128 + hc * 16 + l16] = o;
            }
    }
}

extern "C" void kernel_launch(void* const* d_in, const int* in_sizes, int n_in,
                              void* d_out, int out_size, void* d_ws, size_t ws_size,
                              hipStream_t stream) {
    const float* x    = (const float*)d_in[0];
    const float* mask = (const float*)d_in[1];
    const float* Wv   = (const float*)d_in[2];
    const float* bv   = (const float*)d_in[3];
    const float* Wk   = (const float*)d_in[4];
    const float* bk   = (const float*)d_in[5];
    const float* Wq   = (const float*)d_in[6];
    const float* bq   = (const float*)d_in[7];
    float* out = (float*)d_out;

    const size_t BNH = (size_t)BB * NN * HH;
    _Float16* ws  = (_Float16*)d_ws;
    _Float16* vTb = ws;                 // [B][H][N]
    _Float16* kb  = ws + BNH;           // [B][N][H]
    _Float16* qb  = ws + 2 * BNH;       // [B][N][H]

    wtrans_kernel<<<3, 256, 0, stream>>>(Wq, Wk, Wv);
    proj_kernel<<<512, 256, 0, stream>>>(x, bq, bk, bv, qb, kb, vTb);
    attn_kernel<<<dim3(32, 32), 256, 0, stream>>>(qb, kb, vTb, mask, out);
}